// Round 8
// baseline (158.798 us; speedup 1.0000x reference)
//
#include <hip/hip_runtime.h>
#include <stdint.h>

typedef __bf16 bf16;
typedef __bf16 bf16x8 __attribute__((ext_vector_type(8)));
typedef float f32x4 __attribute__((ext_vector_type(4)));

struct alignas(8) U16x4 { uint16_t v[4]; };

__device__ __forceinline__ f32x4 mfma16(bf16x8 a, bf16x8 b, f32x4 c) {
    return __builtin_amdgcn_mfma_f32_16x16x32_bf16(a, b, c, 0, 0, 0);
}

__device__ __forceinline__ void gload_lds16(const void* g, void* l) {
    __builtin_amdgcn_global_load_lds(
        (const __attribute__((address_space(1))) uint32_t*)g,
        (__attribute__((address_space(3))) uint32_t*)l, 16, 0, 0);
}

__device__ __forceinline__ uint16_t bf_bits(bf16 v) {
    return __builtin_bit_cast(uint16_t, v);
}

__device__ __forceinline__ float bf2f(uint16_t u) {
    uint32_t x = (uint32_t)u << 16;
    return __builtin_bit_cast(float, x);
}

// Q pre-scale: 1/sqrt(64) * log2(e), so attention works in exp2 domain.
#define QSCALE 0.18033688011112042f

// ---------------------------------------------------------------------------
// W prep: Wq/Wk/Wv [512][64] f32 -> fragment-major bf16:
//   wt[p][kt][f][l] : bf16x8 for n=(l&15)+16f, k=kt*32+(l>>4)*8+j.
// ---------------------------------------------------------------------------
__global__ __launch_bounds__(256)
void wprep_kernel(const float* __restrict__ Wq, const float* __restrict__ Wk,
                  const float* __restrict__ Wv, uint16_t* __restrict__ wt)
{
    const int tid = blockIdx.x * 256 + threadIdx.x;   // [0, 12288)
    const int p   = tid >> 12;
    const int rem = tid & 4095;
    const int kt  = rem >> 8;
    const int f   = (rem >> 6) & 3;
    const int l   = rem & 63;
    const int n   = (l & 15) + 16 * f;
    const int k0  = kt * 32 + (l >> 4) * 8;
    const float* W = (p == 0) ? Wq : (p == 1) ? Wk : Wv;
    bf16x8 v;
    #pragma unroll
    for (int j = 0; j < 8; j++)
        v[j] = (bf16)W[(size_t)(k0 + j) * 64 + n];
    *(bf16x8*)(wt + (size_t)tid * 8) = v;
}

// ---------------------------------------------------------------------------
// Projection, DIAGNOSTIC REP version: identical structure to R7; the compute
// (A prefetch + kt loop) repeats REP times, acc reset per rep, dead reps
// kept live with asm sinks. Output uses the final rep only.
// ---------------------------------------------------------------------------
template <int REP>
__global__ __launch_bounds__(256, 2)
void proj_kernel(const float* __restrict__ xq, const float* __restrict__ xk,
                 const float* __restrict__ xv,
                 const float* __restrict__ bq, const float* __restrict__ bk,
                 const float* __restrict__ bv,
                 const uint16_t* __restrict__ wt,
                 uint16_t* __restrict__ q_ws, uint16_t* __restrict__ k_ws,
                 uint16_t* __restrict__ vt_ws)
{
    const int p = blockIdx.y;
    const float* x    = (p == 0) ? xq : (p == 1) ? xk : xv;
    const float* bias = (p == 0) ? bq : (p == 1) ? bk : bv;
    const uint16_t* wtp = wt + (size_t)p * 32768;

    const int m0 = blockIdx.x * 64;
    const int t  = threadIdx.x;
    const int l  = t & 63;
    const int w  = t >> 6;           // 0..3

    __shared__ __align__(16) uint16_t sW[32768];   // 64 KB: [kt][f][l] bf16x8

    const int arow = m0 + w * 16 + (l & 15);       // this lane's A-frag row
    const int kg   = (l >> 4) * 8;                 // k sub-offset in 32-step
    const float* xrow = x + (size_t)arow * 512 + kg;

    float4 av0[8], av1[8];
    auto prefetch_all = [&]() {
        #pragma unroll
        for (int s = 0; s < 8; s++) {
            av0[s] = *(const float4*)(xrow + s * 32);
            av1[s] = *(const float4*)(xrow + s * 32 + 4);
        }
    };

    // ---- A prefetch prologue: depth 8 (16 loads in flight per lane)
    prefetch_all();

    // ---- stage all of W^T into LDS (linear, once): 16 rounds x 256 thr
    #pragma unroll
    for (int r = 0; r < 16; r++)
        gload_lds16(wtp + (size_t)(r * 256 + t) * 8, (char*)sW + (r * 256 + t) * 16);

    __syncthreads();

    f32x4 acc[4];
    const f32x4 zero = {0.f, 0.f, 0.f, 0.f};

    for (int rep = 0; rep < REP; rep++) {
        if (rep) prefetch_all();
        #pragma unroll
        for (int f = 0; f < 4; f++) acc[f] = zero;

        #pragma unroll
        for (int kt = 0; kt < 16; kt++) {
            const int slot = kt & 7;
            bf16x8 a;
            a[0] = (bf16)av0[slot].x; a[1] = (bf16)av0[slot].y;
            a[2] = (bf16)av0[slot].z; a[3] = (bf16)av0[slot].w;
            a[4] = (bf16)av1[slot].x; a[5] = (bf16)av1[slot].y;
            a[6] = (bf16)av1[slot].z; a[7] = (bf16)av1[slot].w;
            if (kt < 8) {
                const int kb = (kt + 8) * 32;
                av0[slot] = *(const float4*)(xrow + kb);
                av1[slot] = *(const float4*)(xrow + kb + 4);
            }
            #pragma unroll
            for (int f = 0; f < 4; f++) {
                bf16x8 bfr = *(const bf16x8*)((const char*)sW + ((kt * 4 + f) * 64 + l) * 16);
                acc[f] = mfma16(a, bfr, acc[f]);
            }
        }

        if (rep < REP - 1) {
            #pragma unroll
            for (int f = 0; f < 4; f++)
                asm volatile("" :: "v"(acc[f][0]), "v"(acc[f][1]),
                                   "v"(acc[f][2]), "v"(acc[f][3]));
        }
    }

    float bv4[4];
    #pragma unroll
    for (int f = 0; f < 4; f++) bv4[f] = bias[16 * f + (l & 15)];

    if (p < 2) {
        uint16_t* outp = (p == 0) ? q_ws : k_ws;
        const float scale = (p == 0) ? QSCALE : 1.0f;
        #pragma unroll
        for (int f = 0; f < 4; f++)
            #pragma unroll
            for (int r = 0; r < 4; r++) {
                const int row = m0 + w * 16 + (l >> 4) * 4 + r;
                const int col = 16 * f + (l & 15);
                outp[(size_t)row * 64 + col] = bf_bits((bf16)((acc[f][r] + bv4[f]) * scale));
            }
    } else {
        #pragma unroll
        for (int f = 0; f < 4; f++) {
            const int row0 = m0 + w * 16 + (l >> 4) * 4;
            const int col  = 16 * f + (l & 15);
            const int bb = row0 >> 11;
            const int s0 = row0 & 2047;
            U16x4 pk;
            #pragma unroll
            for (int r = 0; r < 4; r++)
                pk.v[r] = bf_bits((bf16)(acc[f][r] + bv4[f]));
            *(U16x4*)(vt_ws + ((size_t)bb * 64 + col) * 2048 + s0) = pk;
        }
    }
}

// ---------------------------------------------------------------------------
// Flash attention, DIAGNOSTIC REP version: identical structure to R7; the
// whole NT-tile loop repeats REP times (state reset per rep, re-staged K/V,
// asm sinks keep dead reps live). Output uses the final rep only.
// ---------------------------------------------------------------------------
template <int NCHUNK, int REP>
__global__ __launch_bounds__(512, 4)
void attn_kernel(const uint16_t* __restrict__ q_ws, const uint16_t* __restrict__ k_ws,
                 const uint16_t* __restrict__ vt_ws, float* __restrict__ out,
                 uint16_t* __restrict__ O_part, float* __restrict__ m_arr,
                 float* __restrict__ l_arr)
{
    constexpr int NT = 32 / NCHUNK;  // KV tiles per chunk
    const int qt = blockIdx.x, b = blockIdx.y, c = blockIdx.z;
    const int t = threadIdx.x, l = t & 63, w = t >> 6;   // w: 0..7
    const int q0 = qt * 128;

    __shared__ __align__(16) uint16_t sK[2][64 * 64];  // [s][d] swizzled
    __shared__ __align__(16) uint16_t sV[2][64 * 64];  // [dv][s] swizzled
    __shared__ __align__(16) uint16_t sP[8][16 * 64];  // per-wave P, swizzled

    const uint16_t* qp = q_ws + ((size_t)(b * 2048 + q0)) * 64;
    const uint16_t* kp = k_ws + (size_t)b * 2048 * 64;
    const uint16_t* vp = vt_ws + (size_t)b * 64 * 2048;

    // Q fragments (pre-scaled: scores come out in log2 units)
    bf16x8 aq[2];
    #pragma unroll
    for (int ks = 0; ks < 2; ks++)
        aq[ks] = *(const bf16x8*)(qp + (size_t)(w * 16 + (l & 15)) * 64 + (l >> 4) * 8 + ks * 32);

    const f32x4 zero = {0.f, 0.f, 0.f, 0.f};
    f32x4 acco[4];
    float m_r[4], l_r[4];

    // 512 threads: thread t stages one 16B chunk of K and one of V.
    auto stage = [&](int tile, int buf) {
        const int kv0  = tile * 64;
        const int row  = t >> 3;                    // 0..63
        const int slot = (t & 7) ^ (row & 7);       // inverse swizzle on source
        gload_lds16(kp + (size_t)(kv0 + row) * 64 + slot * 8,
                    (char*)sK[buf] + t * 16);
        gload_lds16(vp + (size_t)row * 2048 + kv0 + slot * 8,
                    (char*)sV[buf] + t * 16);
    };

    stage(c * NT, 0);
    __syncthreads();

    for (int rep = 0; rep < REP; rep++) {
        if (rep) {
            stage(c * NT, 0);
            __syncthreads();
        }
        #pragma unroll
        for (int f = 0; f < 4; f++) acco[f] = zero;
        #pragma unroll
        for (int r = 0; r < 4; r++) { m_r[r] = -__builtin_inff(); l_r[r] = 0.f; }

        for (int i = 0; i < NT; i++) {
            const int buf = i & 1;
            if (i < NT - 1) stage(c * NT + i + 1, buf ^ 1);

            // ---- scores (log2 domain): C row=(l>>4)*4+r, col=(l&15)+16f
            f32x4 accs[4];
            #pragma unroll
            for (int f = 0; f < 4; f++) accs[f] = zero;
            #pragma unroll
            for (int ks = 0; ks < 2; ks++) {
                const int kb = (l >> 4) * 16 + ks * 64;
                #pragma unroll
                for (int f = 0; f < 4; f++) {
                    const int srow = (l & 15) + 16 * f;
                    bf16x8 bk = *(const bf16x8*)((const char*)sK[buf] + srow * 128 + (kb ^ ((srow & 7) << 4)));
                    accs[f] = mfma16(aq[ks], bk, accs[f]);
                }
            }

            // ---- online softmax, exp2 domain, row reduce across 16-lane groups
            float mx[4];
            #pragma unroll
            for (int r = 0; r < 4; r++)
                mx[r] = fmaxf(fmaxf(accs[0][r], accs[1][r]), fmaxf(accs[2][r], accs[3][r]));
            #pragma unroll
            for (int off = 1; off < 16; off <<= 1)
                #pragma unroll
                for (int r = 0; r < 4; r++) mx[r] = fmaxf(mx[r], __shfl_xor(mx[r], off));

            const float grow = fmaxf(fmaxf(mx[0] - m_r[0], mx[1] - m_r[1]),
                                     fmaxf(mx[2] - m_r[2], mx[3] - m_r[3]));
            const bool skip = __all(grow <= 0.f);

            float corr[4];
            if (!skip) {
                #pragma unroll
                for (int r = 0; r < 4; r++) {
                    const float mnew = fmaxf(m_r[r], mx[r]);
                    corr[r] = exp2f(m_r[r] - mnew);
                    m_r[r] = mnew;
                }
            }

            float rs[4] = {0.f, 0.f, 0.f, 0.f};
            bf16 pb[4][4];
            #pragma unroll
            for (int f = 0; f < 4; f++)
                #pragma unroll
                for (int r = 0; r < 4; r++) {
                    const float pv = exp2f(accs[f][r] - m_r[r]);
                    rs[r] += pv;
                    pb[f][r] = (bf16)pv;
                }
            #pragma unroll
            for (int off = 1; off < 16; off <<= 1)
                #pragma unroll
                for (int r = 0; r < 4; r++) rs[r] += __shfl_xor(rs[r], off);

            if (!skip) {
                #pragma unroll
                for (int r = 0; r < 4; r++) l_r[r] = l_r[r] * corr[r] + rs[r];
                #pragma unroll
                for (int f = 0; f < 4; f++)
                    #pragma unroll
                    for (int r = 0; r < 4; r++) acco[f][r] *= corr[r];
            } else {
                #pragma unroll
                for (int r = 0; r < 4; r++) l_r[r] += rs[r];
            }

            // ---- P to LDS (C layout -> A layout round trip), per-wave region
            #pragma unroll
            for (int f = 0; f < 4; f++)
                #pragma unroll
                for (int r = 0; r < 4; r++) {
                    const int row = (l >> 4) * 4 + r;
                    const int col = (l & 15) + 16 * f;
                    const int byte = row * 128 + ((col * 2) ^ ((row & 7) << 4));
                    *(bf16*)((char*)sP[w] + byte) = pb[f][r];
                }
            asm volatile("s_waitcnt lgkmcnt(0)" ::: "memory");

            // ---- PV
            #pragma unroll
            for (int ks = 0; ks < 2; ks++) {
                const int kb = (l >> 4) * 16 + ks * 64;
                const int prow = l & 15;
                bf16x8 ap = *(const bf16x8*)((const char*)sP[w] + prow * 128 + (kb ^ ((prow & 7) << 4)));
                #pragma unroll
                for (int f = 0; f < 4; f++) {
                    const int vrow = (l & 15) + 16 * f;
                    bf16x8 bv2 = *(const bf16x8*)((const char*)sV[buf] + vrow * 128 + (kb ^ ((vrow & 7) << 4)));
                    acco[f] = mfma16(ap, bv2, acco[f]);
                }
            }
            __syncthreads();
        }

        if (rep < REP - 1) {
            #pragma unroll
            for (int f = 0; f < 4; f++)
                asm volatile("" :: "v"(acco[f][0]), "v"(acco[f][1]),
                                   "v"(acco[f][2]), "v"(acco[f][3]));
            #pragma unroll
            for (int r = 0; r < 4; r++)
                asm volatile("" :: "v"(l_r[r]), "v"(m_r[r]));
        }
    }

    if constexpr (NCHUNK == 1) {
        #pragma unroll
        for (int f = 0; f < 4; f++)
            #pragma unroll
            for (int r = 0; r < 4; r++) {
                const int qrow = q0 + w * 16 + (l >> 4) * 4 + r;
                const int col  = 16 * f + (l & 15);
                out[((size_t)(b * 2048 + qrow)) * 64 + col] = acco[f][r] / l_r[r];
            }
    } else {
        #pragma unroll
        for (int f = 0; f < 4; f++)
            #pragma unroll
            for (int r = 0; r < 4; r++) {
                const int qrow = q0 + w * 16 + (l >> 4) * 4 + r;
                const int col  = 16 * f + (l & 15);
                O_part[((size_t)c * 16384 + b * 2048 + qrow) * 64 + col] =
                    bf_bits((bf16)acco[f][r]);
            }
        if ((l & 15) == 0) {
            #pragma unroll
            for (int r = 0; r < 4; r++) {
                const size_t idx = (size_t)c * 16384 + b * 2048 + q0 + w * 16 + (l >> 4) * 4 + r;
                m_arr[idx] = m_r[r];
                l_arr[idx] = l_r[r];
            }
        }
    }
}

// ---------------------------------------------------------------------------
// Combine: merge NCHUNK=4 bf16 partials (exp2-domain m). Grid (128, 8).
// ---------------------------------------------------------------------------
__global__ __launch_bounds__(256, 8)
void combine_kernel(const uint16_t* __restrict__ O_part, const float* __restrict__ m_arr,
                    const float* __restrict__ l_arr, float* __restrict__ out)
{
    const int b = blockIdx.y;
    const int r0 = (blockIdx.x >> 2) * 64 + (blockIdx.x & 3) * 16;
    const int t = threadIdx.x;
    const int col = t & 63;
    const int rg = t >> 6;

    #pragma unroll
    for (int pass = 0; pass < 4; pass++) {
        const int qrow = r0 + pass * 4 + rg;
        const size_t ridx = (size_t)b * 2048 + qrow;
        float m[4], lv[4];
        #pragma unroll
        for (int c = 0; c < 4; c++) {
            m[c]  = m_arr[(size_t)c * 16384 + ridx];
            lv[c] = l_arr[(size_t)c * 16384 + ridx];
        }
        const float M = fmaxf(fmaxf(m[0], m[1]), fmaxf(m[2], m[3]));
        float L = 0.f, wgt[4];
        #pragma unroll
        for (int c = 0; c < 4; c++) { wgt[c] = exp2f(m[c] - M); L += lv[c] * wgt[c]; }
        float acc = 0.f;
        #pragma unroll
        for (int c = 0; c < 4; c++)
            acc += bf2f(O_part[((size_t)c * 16384 + ridx) * 64 + col]) * wgt[c];
        out[ridx * 64 + col] = acc / L;
    }
}

// ---------------------------------------------------------------------------
extern "C" void kernel_launch(void* const* d_in, const int* in_sizes, int n_in,
                              void* d_out, int out_size, void* d_ws, size_t ws_size,
                              hipStream_t stream) {
    const float* xq = (const float*)d_in[0];
    const float* xk = (const float*)d_in[1];
    const float* xv = (const float*)d_in[2];
    const float* Wq = (const float*)d_in[3];
    const float* bq = (const float*)d_in[4];
    const float* Wk = (const float*)d_in[5];
    const float* bk = (const float*)d_in[6];
    const float* Wv = (const float*)d_in[7];
    const float* bv = (const float*)d_in[8];

    uint16_t* q_ws  = (uint16_t*)d_ws;
    uint16_t* k_ws  = q_ws + (size_t)16384 * 64;
    uint16_t* vt_ws = k_ws + (size_t)16384 * 64;
    uint16_t* wt    = vt_ws + (size_t)16384 * 64;               // 3*4096*8 bf16
    uint16_t* O_part = wt + (size_t)3 * 4096 * 8;               // bf16, 8.4 MB
    float* m_arr  = (float*)(O_part + (size_t)4 * 16384 * 64);
    float* l_arr  = m_arr + (size_t)4 * 16384;
    float* out = (float*)d_out;

    const size_t need = (size_t)3 * 16384 * 64 * 2            // q,k,vt bf16
                      + (size_t)3 * 4096 * 8 * 2              // wt
                      + (size_t)4 * 16384 * 64 * 2            // O_part bf16
                      + (size_t)2 * 4 * 16384 * 4;            // m,l

    wprep_kernel<<<48, 256, 0, stream>>>(Wq, Wk, Wv, wt);
    // DIAGNOSTIC: REP=3 on proj, REP=4 on attn to surface them in rocprof
    // top-5 above the harness's 39us fillBuffer dispatches.
    proj_kernel<3><<<dim3(256, 3), 256, 0, stream>>>(xq, xk, xv, bq, bk, bv, wt,
                                                     q_ws, k_ws, vt_ws);
    if (ws_size >= need) {
        attn_kernel<4, 4><<<dim3(16, 8, 4), 512, 0, stream>>>(q_ws, k_ws, vt_ws, out,
                                                              O_part, m_arr, l_arr);
        combine_kernel<<<dim3(128, 8), 256, 0, stream>>>(O_part, m_arr, l_arr, out);
    } else {
        attn_kernel<1, 1><<<dim3(16, 8, 1), 512, 0, stream>>>(q_ws, k_ws, vt_ws, out,
                                                              nullptr, nullptr, nullptr);
    }
}

// Round 9
// 55.790 us; speedup vs baseline: 2.8463x; 2.8463x over previous
//
#include <hip/hip_runtime.h>
#include <stdint.h>

typedef __bf16 bf16;
typedef __bf16 bf16x8 __attribute__((ext_vector_type(8)));
typedef float f32x4 __attribute__((ext_vector_type(4)));

struct alignas(8) U16x4 { uint16_t v[4]; };

__device__ __forceinline__ f32x4 mfma16(bf16x8 a, bf16x8 b, f32x4 c) {
    return __builtin_amdgcn_mfma_f32_16x16x32_bf16(a, b, c, 0, 0, 0);
}

__device__ __forceinline__ void gload_lds16(const void* g, void* l) {
    __builtin_amdgcn_global_load_lds(
        (const __attribute__((address_space(1))) uint32_t*)g,
        (__attribute__((address_space(3))) uint32_t*)l, 16, 0, 0);
}

__device__ __forceinline__ uint16_t bf_bits(bf16 v) {
    return __builtin_bit_cast(uint16_t, v);
}

__device__ __forceinline__ float bf2f(uint16_t u) {
    uint32_t x = (uint32_t)u << 16;
    return __builtin_bit_cast(float, x);
}

// Q pre-scale: 1/sqrt(64) * log2(e), so attention works in exp2 domain.
#define QSCALE 0.18033688011112042f

// ---------------------------------------------------------------------------
// W prep: Wq/Wk/Wv [512][64] f32 -> fragment-major bf16:
//   wt[p][kt][f][l] : bf16x8 for n=(l&15)+16f, k=kt*32+(l>>4)*8+j.
// ---------------------------------------------------------------------------
__global__ __launch_bounds__(256)
void wprep_kernel(const float* __restrict__ Wq, const float* __restrict__ Wk,
                  const float* __restrict__ Wv, uint16_t* __restrict__ wt)
{
    const int tid = blockIdx.x * 256 + threadIdx.x;   // [0, 12288)
    const int p   = tid >> 12;
    const int rem = tid & 4095;
    const int kt  = rem >> 8;
    const int f   = (rem >> 6) & 3;
    const int l   = rem & 63;
    const int n   = (l & 15) + 16 * f;
    const int k0  = kt * 32 + (l >> 4) * 8;
    const float* W = (p == 0) ? Wq : (p == 1) ? Wk : Wv;
    bf16x8 v;
    #pragma unroll
    for (int j = 0; j < 8; j++)
        v[j] = (bf16)W[(size_t)(k0 + j) * 64 + n];
    *(bf16x8*)(wt + (size_t)tid * 8) = v;
}

// ---------------------------------------------------------------------------
// Projection: out = x @ W + b.  BM=64, 256 threads (4 waves x 16 rows),
// grid 256x3 = 768 blocks = 3 blocks/CU. W^T staged once per block into LDS;
// A-fragments direct from global with depth-8 static prefetch.
// q pre-scaled by QSCALE. v stored transposed [8][64][2048].
// ---------------------------------------------------------------------------
__global__ __launch_bounds__(256, 2)
void proj_kernel(const float* __restrict__ xq, const float* __restrict__ xk,
                 const float* __restrict__ xv,
                 const float* __restrict__ bq, const float* __restrict__ bk,
                 const float* __restrict__ bv,
                 const uint16_t* __restrict__ wt,
                 uint16_t* __restrict__ q_ws, uint16_t* __restrict__ k_ws,
                 uint16_t* __restrict__ vt_ws)
{
    const int p = blockIdx.y;
    const float* x    = (p == 0) ? xq : (p == 1) ? xk : xv;
    const float* bias = (p == 0) ? bq : (p == 1) ? bk : bv;
    const uint16_t* wtp = wt + (size_t)p * 32768;

    const int m0 = blockIdx.x * 64;
    const int t  = threadIdx.x;
    const int l  = t & 63;
    const int w  = t >> 6;           // 0..3

    __shared__ __align__(16) uint16_t sW[32768];   // 64 KB: [kt][f][l] bf16x8

    const int arow = m0 + w * 16 + (l & 15);       // this lane's A-frag row
    const int kg   = (l >> 4) * 8;                 // k sub-offset in 32-step
    const float* xrow = x + (size_t)arow * 512 + kg;

    // ---- A prefetch prologue: depth 8 (16 loads in flight per lane)
    float4 av0[8], av1[8];
    #pragma unroll
    for (int s = 0; s < 8; s++) {
        av0[s] = *(const float4*)(xrow + s * 32);
        av1[s] = *(const float4*)(xrow + s * 32 + 4);
    }

    // ---- stage all of W^T into LDS (linear, once): 16 rounds x 256 thr
    #pragma unroll
    for (int r = 0; r < 16; r++)
        gload_lds16(wtp + (size_t)(r * 256 + t) * 8, (char*)sW + (r * 256 + t) * 16);

    __syncthreads();

    f32x4 acc[4];
    const f32x4 zero = {0.f, 0.f, 0.f, 0.f};
    #pragma unroll
    for (int f = 0; f < 4; f++) acc[f] = zero;

    #pragma unroll
    for (int kt = 0; kt < 16; kt++) {
        const int slot = kt & 7;
        bf16x8 a;
        a[0] = (bf16)av0[slot].x; a[1] = (bf16)av0[slot].y;
        a[2] = (bf16)av0[slot].z; a[3] = (bf16)av0[slot].w;
        a[4] = (bf16)av1[slot].x; a[5] = (bf16)av1[slot].y;
        a[6] = (bf16)av1[slot].z; a[7] = (bf16)av1[slot].w;
        if (kt < 8) {
            const int kb = (kt + 8) * 32;
            av0[slot] = *(const float4*)(xrow + kb);
            av1[slot] = *(const float4*)(xrow + kb + 4);
        }
        #pragma unroll
        for (int f = 0; f < 4; f++) {
            bf16x8 bfr = *(const bf16x8*)((const char*)sW + ((kt * 4 + f) * 64 + l) * 16);
            acc[f] = mfma16(a, bfr, acc[f]);
        }
    }

    float bv4[4];
    #pragma unroll
    for (int f = 0; f < 4; f++) bv4[f] = bias[16 * f + (l & 15)];

    if (p < 2) {
        uint16_t* outp = (p == 0) ? q_ws : k_ws;
        const float scale = (p == 0) ? QSCALE : 1.0f;
        #pragma unroll
        for (int f = 0; f < 4; f++)
            #pragma unroll
            for (int r = 0; r < 4; r++) {
                const int row = m0 + w * 16 + (l >> 4) * 4 + r;
                const int col = 16 * f + (l & 15);
                outp[(size_t)row * 64 + col] = bf_bits((bf16)((acc[f][r] + bv4[f]) * scale));
            }
    } else {
        #pragma unroll
        for (int f = 0; f < 4; f++) {
            const int row0 = m0 + w * 16 + (l >> 4) * 4;
            const int col  = 16 * f + (l & 15);
            const int bb = row0 >> 11;
            const int s0 = row0 & 2047;
            U16x4 pk;
            #pragma unroll
            for (int r = 0; r < 4; r++)
                pk.v[r] = bf_bits((bf16)(acc[f][r] + bv4[f]));
            *(U16x4*)(vt_ws + ((size_t)bb * 64 + col) * 2048 + s0) = pk;
        }
    }
}

// ---------------------------------------------------------------------------
// Flash attention, SWAPPED QK^T: accs[f] = mfma(K_frag, Q_frag) so lane
// l holds S[kv = f*16 + (l>>4)*4 + r][q = l&15] — the softmax row (over kv)
// is 16 in-register values + a 4-lane butterfly (xor 16/32). P goes to LDS
// as 4x packed 8B writes per lane; PV reads it as the A operand. Everything
// else (staging, V layout, O C-layout, epilogue) unchanged from R7.
// ---------------------------------------------------------------------------
template <int NCHUNK>
__global__ __launch_bounds__(512, 4)
void attn_kernel(const uint16_t* __restrict__ q_ws, const uint16_t* __restrict__ k_ws,
                 const uint16_t* __restrict__ vt_ws, float* __restrict__ out,
                 uint16_t* __restrict__ O_part, float* __restrict__ m_arr,
                 float* __restrict__ l_arr)
{
    constexpr int NT = 32 / NCHUNK;  // KV tiles per chunk
    const int qt = blockIdx.x, b = blockIdx.y, c = blockIdx.z;
    const int t = threadIdx.x, l = t & 63, w = t >> 6;   // w: 0..7
    const int q = l & 15, g = l >> 4;
    const int q0 = qt * 128;

    __shared__ __align__(16) uint16_t sK[2][64 * 64];  // [s][d] swizzled
    __shared__ __align__(16) uint16_t sV[2][64 * 64];  // [dv][s] swizzled
    __shared__ __align__(16) uint16_t sP[8][16 * 64];  // per-wave P [q][kv], swizzled

    const uint16_t* qp = q_ws + ((size_t)(b * 2048 + q0)) * 64;
    const uint16_t* kp = k_ws + (size_t)b * 2048 * 64;
    const uint16_t* vp = vt_ws + (size_t)b * 64 * 2048;

    // Q fragments (pre-scaled: scores come out in log2 units)
    bf16x8 aq[2];
    #pragma unroll
    for (int ks = 0; ks < 2; ks++)
        aq[ks] = *(const bf16x8*)(qp + (size_t)(w * 16 + q) * 64 + g * 8 + ks * 32);

    const f32x4 zero = {0.f, 0.f, 0.f, 0.f};
    f32x4 acco[4];
    #pragma unroll
    for (int f = 0; f < 4; f++) acco[f] = zero;
    float m_st = -__builtin_inff();   // running max for q-row (l&15)
    float l_st = 0.f;                 // running sum for q-row (l&15)

    // 512 threads: thread t stages one 16B chunk of K and one of V.
    auto stage = [&](int tile, int buf) {
        const int kv0  = tile * 64;
        const int row  = t >> 3;                    // 0..63
        const int slot = (t & 7) ^ (row & 7);       // inverse swizzle on source
        gload_lds16(kp + (size_t)(kv0 + row) * 64 + slot * 8,
                    (char*)sK[buf] + t * 16);
        gload_lds16(vp + (size_t)row * 2048 + kv0 + slot * 8,
                    (char*)sV[buf] + t * 16);
    };

    stage(c * NT, 0);
    __syncthreads();

    for (int i = 0; i < NT; i++) {
        const int buf = i & 1;
        if (i < NT - 1) stage(c * NT + i + 1, buf ^ 1);

        // ---- scores, swapped: accs[f][r] = S[kv=f*16+g*4+r][q]  (log2 dom.)
        f32x4 accs[4];
        #pragma unroll
        for (int f = 0; f < 4; f++) accs[f] = zero;
        #pragma unroll
        for (int ks = 0; ks < 2; ks++) {
            const int kb = g * 16 + ks * 64;
            #pragma unroll
            for (int f = 0; f < 4; f++) {
                const int srow = q + 16 * f;   // kv row in LDS
                bf16x8 bk = *(const bf16x8*)((const char*)sK[buf] + srow * 128 + (kb ^ ((srow & 7) << 4)));
                accs[f] = mfma16(bk, aq[ks], accs[f]);   // A=K, B=Q
            }
        }

        // ---- per-lane softmax over 16 regs + 4-lane butterfly
        float mx = accs[0][0];
        #pragma unroll
        for (int f = 0; f < 4; f++)
            #pragma unroll
            for (int r = 0; r < 4; r++) mx = fmaxf(mx, accs[f][r]);
        mx = fmaxf(mx, __shfl_xor(mx, 16));
        mx = fmaxf(mx, __shfl_xor(mx, 32));

        const bool skip = __all(mx <= m_st);
        float corr = 1.f;
        if (!skip) {
            const float mnew = fmaxf(m_st, mx);
            corr = exp2f(m_st - mnew);
            m_st = mnew;
        }

        // ---- P = exp2(S - m), packed bf16 write (4x 8B per lane)
        float rs = 0.f;
        #pragma unroll
        for (int f = 0; f < 4; f++) {
            U16x4 pk;
            #pragma unroll
            for (int r = 0; r < 4; r++) {
                const float pv = exp2f(accs[f][r] - m_st);
                rs += pv;
                pk.v[r] = bf_bits((bf16)pv);
            }
            const int byte = q * 128 + ((32 * f + 8 * g) ^ ((q & 7) << 4));
            *(U16x4*)((char*)sP[w] + byte) = pk;
        }
        rs += __shfl_xor(rs, 16);
        rs += __shfl_xor(rs, 32);

        if (!skip) {
            l_st = l_st * corr + rs;
            #pragma unroll
            for (int r = 0; r < 4; r++) {
                const float cb = __shfl(corr, (g * 4 + r) + (l & 48));
                #pragma unroll
                for (int f = 0; f < 4; f++) acco[f][r] *= cb;
            }
        } else {
            l_st += rs;
        }

        asm volatile("s_waitcnt lgkmcnt(0)" ::: "memory");

        // ---- PV: A = P[q][kv] from sP, B = V^T rows (dv) from sV
        #pragma unroll
        for (int ks = 0; ks < 2; ks++) {
            bf16x8 ap = *(const bf16x8*)((const char*)sP[w] + q * 128 + ((ks * 64 + g * 16) ^ ((q & 7) << 4)));
            const int kb = g * 16 + ks * 64;
            #pragma unroll
            for (int f = 0; f < 4; f++) {
                const int vrow = q + 16 * f;   // dv row in LDS
                bf16x8 bv2 = *(const bf16x8*)((const char*)sV[buf] + vrow * 128 + (kb ^ ((vrow & 7) << 4)));
                acco[f] = mfma16(ap, bv2, acco[f]);
            }
        }
        __syncthreads();
    }

    if constexpr (NCHUNK == 1) {
        #pragma unroll
        for (int r = 0; r < 4; r++) {
            const float lb = __shfl(l_st, (g * 4 + r) + (l & 48));
            #pragma unroll
            for (int f = 0; f < 4; f++) {
                const int qrow = q0 + w * 16 + g * 4 + r;
                const int col  = 16 * f + q;
                out[((size_t)(b * 2048 + qrow)) * 64 + col] = acco[f][r] / lb;
            }
        }
    } else {
        #pragma unroll
        for (int f = 0; f < 4; f++)
            #pragma unroll
            for (int r = 0; r < 4; r++) {
                const int qrow = q0 + w * 16 + g * 4 + r;
                const int col  = 16 * f + q;
                O_part[((size_t)c * 16384 + b * 2048 + qrow) * 64 + col] =
                    bf_bits((bf16)acco[f][r]);
            }
        if (l < 16) {
            const size_t idx = (size_t)c * 16384 + b * 2048 + q0 + w * 16 + l;
            m_arr[idx] = m_st;
            l_arr[idx] = l_st;
        }
    }
}

// ---------------------------------------------------------------------------
// Combine: merge NCHUNK=4 bf16 partials (exp2-domain m). Grid (128, 8).
// ---------------------------------------------------------------------------
__global__ __launch_bounds__(256, 8)
void combine_kernel(const uint16_t* __restrict__ O_part, const float* __restrict__ m_arr,
                    const float* __restrict__ l_arr, float* __restrict__ out)
{
    const int b = blockIdx.y;
    const int r0 = (blockIdx.x >> 2) * 64 + (blockIdx.x & 3) * 16;
    const int t = threadIdx.x;
    const int col = t & 63;
    const int rg = t >> 6;

    #pragma unroll
    for (int pass = 0; pass < 4; pass++) {
        const int qrow = r0 + pass * 4 + rg;
        const size_t ridx = (size_t)b * 2048 + qrow;
        float m[4], lv[4];
        #pragma unroll
        for (int c = 0; c < 4; c++) {
            m[c]  = m_arr[(size_t)c * 16384 + ridx];
            lv[c] = l_arr[(size_t)c * 16384 + ridx];
        }
        const float M = fmaxf(fmaxf(m[0], m[1]), fmaxf(m[2], m[3]));
        float L = 0.f, wgt[4];
        #pragma unroll
        for (int c = 0; c < 4; c++) { wgt[c] = exp2f(m[c] - M); L += lv[c] * wgt[c]; }
        float acc = 0.f;
        #pragma unroll
        for (int c = 0; c < 4; c++)
            acc += bf2f(O_part[((size_t)c * 16384 + ridx) * 64 + col]) * wgt[c];
        out[ridx * 64 + col] = acc / L;
    }
}

// ---------------------------------------------------------------------------
extern "C" void kernel_launch(void* const* d_in, const int* in_sizes, int n_in,
                              void* d_out, int out_size, void* d_ws, size_t ws_size,
                              hipStream_t stream) {
    const float* xq = (const float*)d_in[0];
    const float* xk = (const float*)d_in[1];
    const float* xv = (const float*)d_in[2];
    const float* Wq = (const float*)d_in[3];
    const float* bq = (const float*)d_in[4];
    const float* Wk = (const float*)d_in[5];
    const float* bk = (const float*)d_in[6];
    const float* Wv = (const float*)d_in[7];
    const float* bv = (const float*)d_in[8];

    uint16_t* q_ws  = (uint16_t*)d_ws;
    uint16_t* k_ws  = q_ws + (size_t)16384 * 64;
    uint16_t* vt_ws = k_ws + (size_t)16384 * 64;
    uint16_t* wt    = vt_ws + (size_t)16384 * 64;               // 3*4096*8 bf16
    uint16_t* O_part = wt + (size_t)3 * 4096 * 8;               // bf16, 8.4 MB
    float* m_arr  = (float*)(O_part + (size_t)4 * 16384 * 64);
    float* l_arr  = m_arr + (size_t)4 * 16384;
    float* out = (float*)d_out;

    const size_t need = (size_t)3 * 16384 * 64 * 2            // q,k,vt bf16
                      + (size_t)3 * 4096 * 8 * 2              // wt
                      + (size_t)4 * 16384 * 64 * 2            // O_part bf16
                      + (size_t)2 * 4 * 16384 * 4;            // m,l

    wprep_kernel<<<48, 256, 0, stream>>>(Wq, Wk, Wv, wt);
    proj_kernel<<<dim3(256, 3), 256, 0, stream>>>(xq, xk, xv, bq, bk, bv, wt,
                                                  q_ws, k_ws, vt_ws);
    if (ws_size >= need) {
        attn_kernel<4><<<dim3(16, 8, 4), 512, 0, stream>>>(q_ws, k_ws, vt_ws, out,
                                                           O_part, m_arr, l_arr);
        combine_kernel<<<dim3(128, 8), 256, 0, stream>>>(O_part, m_arr, l_arr, out);
    } else {
        attn_kernel<1><<<dim3(16, 8, 1), 512, 0, stream>>>(q_ws, k_ws, vt_ws, out,
                                                           nullptr, nullptr, nullptr);
    }
}